// Round 10
// baseline (2085.103 us; speedup 1.0000x reference)
//
#include <hip/hip_runtime.h>

#define HIDDEN 128
#define TSTEPS 512
#define NFUT 50
#define NSTEPS (TSTEPS + NFUT)   // 562 cell steps per group
#define BR 16          // rows/block: G0 = rows 0-7, G1 = rows 8-15 (independent chains)
#define THREADS 1024   // 16 waves: 0-7 MFMA-role, 8-15 ew-role -> 2+2 per SIMD
#define HPITCH 136     // h row pitch bf16 (272B)
#define APITCH 132     // gate-segment pitch f32 within an acc row
#define AROW 532       // acc row pitch f32 = 4*APITCH+4 (stride%32=20 -> <=2-way banks)

typedef __bf16 bf16x8 __attribute__((ext_vector_type(8)));
typedef float floatx4 __attribute__((ext_vector_type(4)));
typedef float f32x2 __attribute__((ext_vector_type(2)));

#if defined(__has_builtin)
#  if __has_builtin(__builtin_amdgcn_exp2f)
#    define EXP2F(x) __builtin_amdgcn_exp2f(x)
#  else
#    define EXP2F(x) exp2f(x)
#  endif
#  if __has_builtin(__builtin_amdgcn_rcpf)
#    define RCPF(x) __builtin_amdgcn_rcpf(x)
#  else
#    define RCPF(x) (1.0f / (x))
#  endif
#  if __has_builtin(__builtin_amdgcn_s_setprio)
#    define SETPRIO(p) __builtin_amdgcn_s_setprio(p)
#  else
#    define SETPRIO(p)
#  endif
#else
#  define EXP2F(x) exp2f(x)
#  define RCPF(x) (1.0f / (x))
#  define SETPRIO(p)
#endif

#define L2E  1.4426950408889634f
#define L2E2 2.8853900817779268f

__global__ __launch_bounds__(THREADS, 1)
void lstm_forecast_kernel(const float* __restrict__ x,
                          const float* __restrict__ W_ih,
                          const float* __restrict__ W_hh,
                          const float* __restrict__ b_ih,
                          const float* __restrict__ b_hh,
                          const float* __restrict__ fc_w,
                          const float* __restrict__ fc_b,
                          float* __restrict__ out) {
    // LDS: acc 68KB + h 8.5KB + fcw 1KB + wxc 6KB ~= 84KB -> 1 block/CU
    __shared__ __align__(16) __bf16 h_lds[2][16 * HPITCH];   // per-group h; rows 8-15 stay 0
    __shared__ __align__(16) float  acc_lds[2][16 * AROW];   // per-group raw gates (f32)
    __shared__ __align__(16) float  fcw_lds[2][HIDDEN];
    __shared__ __align__(16) float  wxc_lds[3][4 * HIDDEN];  // gs-scaled {W_ih0, W_ih1, b}

    const int tid  = threadIdx.x;
    const int wave = tid >> 6;          // 0..15; SIMD = wave&3 -> 2 MFMA + 2 ew waves/SIMD
    const int lane = tid & 63;
    const int quad = lane >> 4;
    const int l15  = lane & 15;
    const int rb   = blockIdx.x * BR;
    const bool mrole = (wave < 8);      // waves 0-7: MFMA producers; 8-15: ew consumers
    const int erow = lane & 7;                       // ew: row within group
    const int cp   = (wave - 8) * 8 + (lane >> 3);   // ew: col-pair 0..63 (cols 2cp,2cp+1)
    const int cbase = wave * 16 + quad * 4;          // mrole: C-layout col base

    const float fcb0 = fc_b[0], fcb1 = fc_b[1];
    if (tid < 256) fcw_lds[tid >> 7][tid & 127] = fc_w[tid];
    if (tid < 512) {                    // gs-scaled x-path weights, C-layout friendly
        const float g = ((tid >> 7) == 2) ? -L2E2 : -L2E;
        wxc_lds[0][tid] = g * W_ih[tid * 2 + 0];
        wxc_lds[1][tid] = g * W_ih[tid * 2 + 1];
        wxc_lds[2][tid] = g * (b_ih[tid] + b_hh[tid]);
    }
    // zero both h buffers fully (rows 8-15 are permanent zero-padding for N=16 MFMA)
    for (int i = tid; i < 2 * 16 * HPITCH; i += THREADS) (&h_lds[0][0])[i] = (__bf16)0.0f;

    // ---- MFMA-role: W_hh -> registers, pre-scaled so MFMA outputs are exp2-ready ----
    // Transposed MFMA: A = weights (m = gate col = wave*16+l15), B = h rows (n = l15).
    // C layout: n(=l15) = tile row (0-7 real for the active group), m(=quad*4+r) = col.
    bf16x8 bfrag[4][4];   // [gate][kchunk] gs-scaled W_hh — 64 VGPRs (R3-proven footprint)
    if (mrole) {
        const int ub = wave * 16 + l15;
#pragma unroll
        for (int g = 0; g < 4; ++g) {
            const float gsg = (g == 2) ? -L2E2 : -L2E;
#pragma unroll
            for (int ks = 0; ks < 4; ++ks) {
                const float* wp = W_hh + (size_t)(g * HIDDEN + ub) * HIDDEN + ks * 32 + quad * 8;
                bf16x8 bb;
#pragma unroll
                for (int j = 0; j < 8; ++j) bb[j] = (__bf16)(gsg * wp[j]);
                bfrag[g][ks] = bb;
            }
        }
    }

    // exact-fp32 C-init: acc(row,col) = gs*(b[col] + w0[col]*x0[row] + w1[col]*x1[row]).
    // Broadcast LDS reads (no l15 dependence) -> conflict-free; VALU on the MFMA waves'
    // underused issue slots. Replaces the x-MFMAs (-20% matrix work).
    auto cinit = [&](float x0, float x1, floatx4* acc4) {
#pragma unroll
        for (int g = 0; g < 4; ++g) {
            const floatx4 w0 = *(const floatx4*)&wxc_lds[0][g * HIDDEN + cbase];
            const floatx4 w1 = *(const floatx4*)&wxc_lds[1][g * HIDDEN + cbase];
            const floatx4 bs = *(const floatx4*)&wxc_lds[2][g * HIDDEN + cbase];
            acc4[g] = bs + w0 * x0 + w1 * x1;
        }
    };

    // MFMA producer iteration for group gp, cell step s (encode s<512, forecast after).
    // Forecast: y = fc.h computed in-register (quad shfl-reduce), emitted, fed as x.
    auto MFMA_iter = [&](int gp, int s, float2& xn) {
        bf16x8 af[4];
#pragma unroll
        for (int ks = 0; ks < 4; ++ks)
            af[ks] = *(const bf16x8*)&h_lds[gp][l15 * HPITCH + ks * 32 + quad * 8];
        float x0, x1;
        if (s < TSTEPS) {
            x0 = xn.x; x1 = xn.y;
            if (s + 1 < TSTEPS)   // prefetch next same-group step (2 iters of latency slack)
                xn = *(const float2*)&x[(size_t)(rb + gp * 8 + (l15 & 7)) * (2 * TSTEPS) + (s + 1) * 2];
        } else {
            float p0 = 0.f, p1 = 0.f;   // y for row l15 from this wave's af slice
#pragma unroll
            for (int ks = 0; ks < 4; ++ks)
#pragma unroll
                for (int j = 0; j < 8; ++j) {
                    const float hv = (float)af[ks][j];
                    p0 += hv * fcw_lds[0][ks * 32 + quad * 8 + j];
                    p1 += hv * fcw_lds[1][ks * 32 + quad * 8 + j];
                }
            p0 += __shfl_xor(p0, 16); p0 += __shfl_xor(p0, 32);
            p1 += __shfl_xor(p1, 16); p1 += __shfl_xor(p1, 32);
            p0 += fcb0; p1 += fcb1;
            if (wave == 0 && quad == 0 && l15 < 8) {
                float2 yv; yv.x = p0; yv.y = p1;
                *(float2*)&out[(size_t)(rb + gp * 8 + l15) * (2 * NFUT) + (s - TSTEPS) * 2] = yv;
            }
            x0 = p0; x1 = p1;
        }
        floatx4 acc4[4];
        cinit(x0, x1, acc4);
        SETPRIO(1);
#pragma unroll
        for (int ks = 0; ks < 4; ++ks)       // ks-outer/g-inner: 4 independent chains
#pragma unroll
            for (int g = 0; g < 4; ++g)
                acc4[g] = __builtin_amdgcn_mfma_f32_16x16x32_bf16(bfrag[g][ks], af[ks], acc4[g], 0, 0, 0);
        SETPRIO(0);
        if (l15 < 8) {                        // rows 8-15 are padding output: drop
#pragma unroll
            for (int g = 0; g < 4; ++g)
                *(floatx4*)&acc_lds[gp][l15 * AROW + g * APITCH + cbase] = acc4[g];
        }
    };

    // ---- ew consumer: one cell-pair per thread; math identical to R3 (absmax-stable) ----
    f32x2 cstA = {0.f, 0.f}, cstB = {0.f, 0.f};   // per-group cell state (static-indexed)
    auto EW = [&](int gp, f32x2& c) {
        const float* ab = &acc_lds[gp][erow * AROW + 2 * cp];
        const f32x2 gi = *(const f32x2*)&ab[0 * APITCH];
        const f32x2 gf = *(const f32x2*)&ab[1 * APITCH];
        const f32x2 gg = *(const f32x2*)&ab[2 * APITCH];
        const f32x2 go = *(const f32x2*)&ab[3 * APITCH];
        f32x2 ea, ec, eb, eo;
        ea.x = EXP2F(gi.x); ea.y = EXP2F(gi.y);   // e^-i
        ec.x = EXP2F(gf.x); ec.y = EXP2F(gf.y);   // e^-f
        eb.x = EXP2F(gg.x); eb.y = EXP2F(gg.y);   // e^-2g
        eo.x = EXP2F(go.x); eo.y = EXP2F(go.y);   // e^-o
        const f32x2 A1 = 1.f + ea, B1 = 1.f + eb, C1 = 1.f + ec;
        const f32x2 P  = A1 * B1;
        const f32x2 PC = P * C1;
        f32x2 R;                                  // batched: 1 rcp for the pair
        { const float I = RCPF(PC.x * PC.y); R.x = I * PC.y; R.y = I * PC.x; }
        const f32x2 sfv = P * R;                  // sigmoid(f)
        const f32x2 igv = (1.f - eb) * (C1 * R);  // sigmoid(i)*tanh(g)
        const f32x2 cn  = sfv * c + igv;
        c = cn;
        const f32x2 am = -L2E2 * cn;
        f32x2 ed;
        ed.x = EXP2F(fminf(am.x, 29.f));          // c clamped at -10 (tanh err < 4e-9)
        ed.y = EXP2F(fminf(am.y, 29.f));
        const f32x2 E = (1.f + ed) * (1.f + eo);
        f32x2 R2;                                 // batched: 1 rcp for the pair
        { const float J = RCPF(E.x * E.y); R2.x = J * E.y; R2.y = J * E.x; }
        const f32x2 hn = (1.f - ed) * R2;         // sigmoid(o)*tanh(c)
        const unsigned pkd =
            (unsigned)__builtin_bit_cast(unsigned short, (__bf16)hn.x)
          | ((unsigned)__builtin_bit_cast(unsigned short, (__bf16)hn.y) << 16);
        *(unsigned*)&h_lds[gp][erow * HPITCH + 2 * cp] = pkd;   // cols 2cp,2cp+1
    };

    // x prefetch registers (encode)
    float2 xnA = {0.f, 0.f}, xnB = {0.f, 0.f};
    if (mrole) {
        xnA = *(const float2*)&x[(size_t)(rb + 0 + (l15 & 7)) * (2 * TSTEPS)];
        xnB = *(const float2*)&x[(size_t)(rb + 8 + (l15 & 7)) * (2 * TSTEPS)];
    }

    __syncthreads();   // h zero + wxc/fcw staged

    // ================= software pipeline: 1 + 2*562 iterations =================
    // iter 2k+1: MFMA(G1, step k)   || ew consumes G0 gates (step k)   -> h_G0(k+1)
    // iter 2k+2: MFMA(G0, step k+1) || ew consumes G1 gates (step k)   -> h_G1(k+1)
    // Buffers: MFMA writes acc[gp] while ew reads acc[gp^1]; MFMA reads h[gp] while
    // ew writes h[gp^1] — disjoint every iteration, one barrier between iterations.
    if (mrole) MFMA_iter(0, 0, xnA);
    __syncthreads();
    for (int s = 0; s < NSTEPS; ++s) {
        if (mrole) MFMA_iter(1, s, xnB); else EW(0, cstA);
        __syncthreads();
        if (mrole) { if (s + 1 < NSTEPS) MFMA_iter(0, s + 1, xnA); }
        else EW(1, cstB);
        __syncthreads();
    }
}

extern "C" void kernel_launch(void* const* d_in, const int* in_sizes, int n_in,
                              void* d_out, int out_size, void* d_ws, size_t ws_size,
                              hipStream_t stream) {
    const float* x    = (const float*)d_in[0];
    const float* W_ih = (const float*)d_in[1];
    const float* W_hh = (const float*)d_in[2];
    const float* b_ih = (const float*)d_in[3];
    const float* b_hh = (const float*)d_in[4];
    const float* fc_w = (const float*)d_in[5];
    const float* fc_b = (const float*)d_in[6];
    float* out = (float*)d_out;

    const int B = in_sizes[0] / (TSTEPS * 2);   // 4096
    const int grid = B / BR;                    // 256 blocks, 1 per CU
    lstm_forecast_kernel<<<grid, THREADS, 0, stream>>>(x, W_ih, W_hh, b_ih, b_hh, fc_w, fc_b, out);
}

// Round 11
// 1118.165 us; speedup vs baseline: 1.8648x; 1.8648x over previous
//
#include <hip/hip_runtime.h>

#define HIDDEN 128
#define TSTEPS 512
#define NFUT 50
#define NSTEPS (TSTEPS + NFUT)   // 562 steps per group
#define BR 16          // rows/block: G0 = rows 0-7, G1 = rows 8-15 (independent chains)
#define THREADS 512    // 8 waves, 2/SIMD
#define HPITCH 136     // h row pitch bf16 (272B, 16B-aligned)
#define ZROW 16        // zero-padding rows 16..23 (N=16 tile, 8 real rows)

typedef __bf16 bf16x8 __attribute__((ext_vector_type(8)));
typedef float floatx4 __attribute__((ext_vector_type(4)));
typedef float f32x2 __attribute__((ext_vector_type(2)));

#if defined(__has_builtin)
#  if __has_builtin(__builtin_amdgcn_exp2f)
#    define EXP2F(x) __builtin_amdgcn_exp2f(x)
#  else
#    define EXP2F(x) exp2f(x)
#  endif
#  if __has_builtin(__builtin_amdgcn_rcpf)
#    define RCPF(x) __builtin_amdgcn_rcpf(x)
#  else
#    define RCPF(x) (1.0f / (x))
#  endif
#else
#  define EXP2F(x) exp2f(x)
#  define RCPF(x) (1.0f / (x))
#endif

#define L2E  1.4426950408889634f
#define L2E2 2.8853900817779268f

// (512,1): calibrated VGPR-budget model (R3/R4/R6 datapoints): budget = 512 /
// waves-per-EU(bound). (512,2)->128 (R3: 92 ok), (512,4)->64 (R4 spill). (512,1)
// -> 2 waves/EU -> 256 budget; we have only 8 waves (1 block/CU) so occupancy
// is unchanged. NO setprio in the hot path: it fences the MFMA/ew interleave.
__global__ __launch_bounds__(THREADS, 1)
void lstm_forecast_kernel(const float* __restrict__ x,
                          const float* __restrict__ W_ih,
                          const float* __restrict__ W_hh,
                          const float* __restrict__ b_ih,
                          const float* __restrict__ b_hh,
                          const float* __restrict__ fc_w,
                          const float* __restrict__ fc_b,
                          float* __restrict__ out) {
    // LDS: xa 64KB + h 6.4KB + fcw 1KB + wxc 6KB ~= 77.4KB -> 1 block/CU
    __shared__ __align__(16) float2 xa[TSTEPS * BR];         // fp32 x (exact C-init path)
    __shared__ __align__(16) __bf16 h_lds[24 * HPITCH];      // rows 0-15 real, 16-23 zero
    __shared__ __align__(16) float  fcw_lds[2][HIDDEN];
    __shared__ __align__(16) float  wxc_lds[3][4 * HIDDEN];  // gs-scaled {W_ih0, W_ih1, b}

    const int tid  = threadIdx.x;
    const int wave = tid >> 6;          // 0..7, 2 waves/SIMD
    const int lane = tid & 63;
    const int quad = lane >> 4;
    const int l15  = lane & 15;
    const int row8 = l15 & 7;           // real row within a group
    const int hi8  = (l15 >> 3) & 1;    // ew: which col-half of the 4-col C slice
    const int rb   = blockIdx.x * BR;
    const int cbase = wave * 16 + quad * 4;   // C-layout col base

    const float fcb0 = fc_b[0], fcb1 = fc_b[1];
    if (tid < 256) fcw_lds[tid >> 7][tid & 127] = fc_w[tid];
    if (tid < 512) {                    // gs-scaled x-path weights (C-layout friendly)
        const float g = ((tid >> 7) == 2) ? -L2E2 : -L2E;
        wxc_lds[0][tid] = g * W_ih[tid * 2 + 0];
        wxc_lds[1][tid] = g * W_ih[tid * 2 + 1];
        wxc_lds[2][tid] = g * (b_ih[tid] + b_hh[tid]);
    }
    // ---- stage x as fp32: xa[t][row0..15] ----
    {
        const int row = tid & 15;
        for (int tb = tid >> 4; tb < TSTEPS; tb += THREADS >> 4)
            xa[tb * BR + row] = *(const float2*)&x[(size_t)(rb + row) * (2 * TSTEPS) + tb * 2];
    }
    // zero all 24 h rows (16-23 stay zero forever: tile padding)
    for (int i = tid; i < 24 * HPITCH; i += THREADS) h_lds[i] = (__bf16)0.0f;

    // ---- W_hh -> registers, gs-scaled so MFMA outputs are exp2-ready ----
    // Transposed MFMA: A = weights (m = gate col = wave*16+l15), B = h rows (n=l15).
    // C layout: n(=l15) = tile row (0-7 real), m(=quad*4+reg) = col offset.
    bf16x8 bfrag[4][4];   // [gate][kchunk] — 64 VGPRs (R3-proven slice)
    {
        const int ub = wave * 16 + l15;
#pragma unroll
        for (int g = 0; g < 4; ++g) {
            const float gsg = (g == 2) ? -L2E2 : -L2E;
#pragma unroll
            for (int ks = 0; ks < 4; ++ks) {
                const float* wp = W_hh + (size_t)(g * HIDDEN + ub) * HIDDEN + ks * 32 + quad * 8;
                bf16x8 bb;
#pragma unroll
                for (int j = 0; j < 8; ++j) bb[j] = (__bf16)(gsg * wp[j]);
                bfrag[g][ks] = bb;
            }
        }
    }

    auto mk = [](float a, float b) { f32x2 r; r.x = a; r.y = b; return r; };

    // MFMA half-iteration for group G, step s: af <- h[G rows], C-init = exact-fp32
    // gs*(b + W_ih*x) (x from xa, or y=fc.h computed in-register when s>=TSTEPS),
    // then 16 MFMAs (4 independent chains). Results stay in acc REGISTERS.
    auto mfmaCell = [&](const int G, const int s, float2& xd, floatx4 (&acc)[4]) {
        const int brow = (l15 < 8) ? (G * 8 + l15) : (ZROW + row8);
        bf16x8 af[4];
#pragma unroll
        for (int ks = 0; ks < 4; ++ks)
            af[ks] = *(const bf16x8*)&h_lds[brow * HPITCH + ks * 32 + quad * 8];
        float x0, x1;
        if (s < TSTEPS) {
            x0 = xd.x; x1 = xd.y;
            const int ns = (s + 1 < TSTEPS) ? s + 1 : 0;    // prefetch next same-G step
            xd = xa[ns * BR + G * 8 + row8];
        } else {
            // forecast: y = fc.h from af (every wave redundantly; af identical per wave)
            float p0 = 0.f, p1 = 0.f;
#pragma unroll
            for (int ks = 0; ks < 4; ++ks)
#pragma unroll
                for (int j = 0; j < 8; ++j) {
                    const float hv = (float)af[ks][j];
                    p0 += hv * fcw_lds[0][ks * 32 + quad * 8 + j];
                    p1 += hv * fcw_lds[1][ks * 32 + quad * 8 + j];
                }
            p0 += __shfl_xor(p0, 16); p0 += __shfl_xor(p0, 32);
            p1 += __shfl_xor(p1, 16); p1 += __shfl_xor(p1, 32);
            p0 += fcb0; p1 += fcb1;
            if (wave == 0 && quad == 0 && l15 < 8) {
                float2 yv; yv.x = p0; yv.y = p1;
                *(float2*)&out[(size_t)(rb + G * 8 + l15) * (2 * NFUT) + (s - TSTEPS) * 2] = yv;
            }
            x0 = p0; x1 = p1;
        }
#pragma unroll
        for (int g = 0; g < 4; ++g) {      // exact-fp32 C-init (broadcast LDS reads)
            const floatx4 w0 = *(const floatx4*)&wxc_lds[0][g * HIDDEN + cbase];
            const floatx4 w1 = *(const floatx4*)&wxc_lds[1][g * HIDDEN + cbase];
            const floatx4 bs = *(const floatx4*)&wxc_lds[2][g * HIDDEN + cbase];
            acc[g] = bs + w0 * x0 + w1 * x1;
        }
#pragma unroll
        for (int ks = 0; ks < 4; ++ks)     // ks-outer/g-inner: 4 independent chains
#pragma unroll
            for (int g = 0; g < 4; ++g)
                acc[g] = __builtin_amdgcn_mfma_f32_16x16x32_bf16(bfrag[g][ks], af[ks], acc[g], 0, 0, 0);
    };

    // ew half-iteration for group G: consumes PREVIOUS iteration's acc (registers,
    // fully independent of the MFMAs issued above -> scheduler interleaves).
    // xor-8 redistribution (R7-verified): hi8 lanes take cols +2,3 of lane-8.
    f32x2 cstA = {0.f, 0.f}, cstB = {0.f, 0.f};
    auto ewCell = [&](const int G, floatx4 (&ap)[4], f32x2& c) {
        const float s20 = __shfl_xor(ap[0][2], 8), s30 = __shfl_xor(ap[0][3], 8);
        const float s21 = __shfl_xor(ap[1][2], 8), s31 = __shfl_xor(ap[1][3], 8);
        const float s22 = __shfl_xor(ap[2][2], 8), s32 = __shfl_xor(ap[2][3], 8);
        const float s23 = __shfl_xor(ap[3][2], 8), s33 = __shfl_xor(ap[3][3], 8);
        const f32x2 gi = hi8 ? mk(s20, s30) : mk(ap[0][0], ap[0][1]);
        const f32x2 gf = hi8 ? mk(s21, s31) : mk(ap[1][0], ap[1][1]);
        const f32x2 gg = hi8 ? mk(s22, s32) : mk(ap[2][0], ap[2][1]);
        const f32x2 go = hi8 ? mk(s23, s33) : mk(ap[3][0], ap[3][1]);
        f32x2 ea, ec, eb, eo;
        ea.x = EXP2F(gi.x); ea.y = EXP2F(gi.y);   // e^-i
        ec.x = EXP2F(gf.x); ec.y = EXP2F(gf.y);   // e^-f
        eb.x = EXP2F(gg.x); eb.y = EXP2F(gg.y);   // e^-2g
        eo.x = EXP2F(go.x); eo.y = EXP2F(go.y);   // e^-o
        const f32x2 A1 = 1.f + ea, B1 = 1.f + eb, C1 = 1.f + ec;
        const f32x2 P  = A1 * B1;
        const f32x2 PC = P * C1;
        f32x2 R;                                  // batched: 1 rcp for the pair
        { const float I = RCPF(PC.x * PC.y); R.x = I * PC.y; R.y = I * PC.x; }
        const f32x2 sfv = P * R;                  // sigmoid(f)
        const f32x2 igv = (1.f - eb) * (C1 * R);  // sigmoid(i)*tanh(g)
        const f32x2 cn  = sfv * c + igv;
        c = cn;
        const f32x2 am = -L2E2 * cn;
        f32x2 ed;
        ed.x = EXP2F(fminf(am.x, 29.f));          // c clamped at -10 (tanh err < 4e-9)
        ed.y = EXP2F(fminf(am.y, 29.f));
        const f32x2 E = (1.f + ed) * (1.f + eo);
        f32x2 R2;                                 // batched: 1 rcp for the pair
        { const float J = RCPF(E.x * E.y); R2.x = J * E.y; R2.y = J * E.x; }
        const f32x2 hn = (1.f - ed) * R2;         // sigmoid(o)*tanh(c)
        const unsigned pkd =
            (unsigned)__builtin_bit_cast(unsigned short, (__bf16)hn.x)
          | ((unsigned)__builtin_bit_cast(unsigned short, (__bf16)hn.y) << 16);
        // bank-exact: (4*row8 + 2*quad + hi8 + 8*wave) covers 0..31 twice -> 2-way, free
        *(unsigned*)&h_lds[(G * 8 + row8) * HPITCH + cbase + hi8 * 2] = pkd;
    };

    __syncthreads();   // staging (xa, wxc, fcw, h zeros) complete

    float2 xdA = xa[0 * BR + 0 + row8];   // G0 step 0
    float2 xdB = xa[0 * BR + 8 + row8];   // G1 step 0
    floatx4 accA[4], accB[4];

    // ============ interleaved pipeline: 2*562-1 half-iterations ============
    // Each half-iteration: MFMA(group X, step s) — 16 MFMAs in flight — while
    // ew(group Y, prev gates in regs) runs on the VALU. One barrier each (ew's
    // h-write must be visible to the NEXT half-iteration's af reads).
    mfmaCell(0, 0, xdA, accA);            // prologue (no pending ew)
    for (int k = 0; k < NSTEPS - 1; ++k) {
        mfmaCell(1, k, xdB, accB);
        ewCell(0, accA, cstA);            // h[G0] for step k+1
        __syncthreads();
        mfmaCell(0, k + 1, xdA, accA);
        ewCell(1, accB, cstB);            // h[G1] for step k+1
        __syncthreads();
    }
    mfmaCell(1, NSTEPS - 1, xdB, accB);   // emits final y(G1); trailing ews unneeded
}

extern "C" void kernel_launch(void* const* d_in, const int* in_sizes, int n_in,
                              void* d_out, int out_size, void* d_ws, size_t ws_size,
                              hipStream_t stream) {
    const float* x    = (const float*)d_in[0];
    const float* W_ih = (const float*)d_in[1];
    const float* W_hh = (const float*)d_in[2];
    const float* b_ih = (const float*)d_in[3];
    const float* b_hh = (const float*)d_in[4];
    const float* fc_w = (const float*)d_in[5];
    const float* fc_b = (const float*)d_in[6];
    float* out = (float*)d_out;

    const int B = in_sizes[0] / (TSTEPS * 2);   // 4096
    const int grid = B / BR;                    // 256 blocks, 1 per CU
    lstm_forecast_kernel<<<grid, THREADS, 0, stream>>>(x, W_ih, W_hh, b_ih, b_hh, fc_w, fc_b, out);
}

// Round 12
// 490.770 us; speedup vs baseline: 4.2486x; 2.2784x over previous
//
#include <hip/hip_runtime.h>

#define HIDDEN 128
#define TSTEPS 512
#define NFUT 50
#define BR 16          // batch rows per block
#define THREADS 512    // 8 waves, 2/SIMD
#define HPITCH 136     // h row pitch in bf16 (272B rows: 16B-aligned for b128)

typedef __bf16 bf16x8 __attribute__((ext_vector_type(8)));
typedef float floatx4 __attribute__((ext_vector_type(4)));
typedef float f32x2 __attribute__((ext_vector_type(2)));

union B8 { int4 i; bf16x8 v; };

#if defined(__has_builtin)
#  if __has_builtin(__builtin_amdgcn_exp2f)
#    define EXP2F(x) __builtin_amdgcn_exp2f(x)
#  else
#    define EXP2F(x) exp2f(x)
#  endif
#  if __has_builtin(__builtin_amdgcn_rcpf)
#    define RCPF(x) __builtin_amdgcn_rcpf(x)
#  else
#    define RCPF(x) (1.0f / (x))
#  endif
#  if __has_builtin(__builtin_amdgcn_s_setprio)
#    define SETPRIO(p) __builtin_amdgcn_s_setprio(p)
#  else
#    define SETPRIO(p)
#  endif
#else
#  define EXP2F(x) exp2f(x)
#  define RCPF(x) (1.0f / (x))
#  define SETPRIO(p)
#endif

#define L2E  1.4426950408889634f
#define L2E2 2.8853900817779268f

__global__ __launch_bounds__(THREADS, 2)
void lstm_forecast_kernel(const float* __restrict__ x,
                          const float* __restrict__ W_ih,
                          const float* __restrict__ W_hh,
                          const float* __restrict__ b_ih,
                          const float* __restrict__ b_hh,
                          const float* __restrict__ fc_w,
                          const float* __restrict__ fc_b,
                          float* __restrict__ out) {
    // LDS: xa 64KB + h 8.5KB + fcw 1KB ~= 74KB -> 1 block/CU
    __shared__ __align__(16) uint2  xa[TSTEPS * BR];        // (x0h,x1h),(x0r,x1r) bf16 splits
    __shared__ __align__(16) __bf16 h_lds[2][BR * HPITCH];  // double-buffered h
    __shared__ __align__(16) float  fcw_lds[2][HIDDEN];

    const int tid  = threadIdx.x;
    const int wave = tid >> 6;          // 0..7; SIMD = wave&3 -> pairs (0,4),(1,5),(2,6),(3,7)
    const int lane = tid & 63;
    const int quad = lane >> 4;
    const int l15  = lane & 15;
    const int rb   = blockIdx.x * BR;

    if (tid < 256) fcw_lds[tid >> 7][tid & 127] = fc_w[tid];

    // ---- stage x as bf16 hi/lo splits: xa[t][row] (feeds the x-MFMA) ----
    {
        const int row = tid & 15;
        for (int tb = tid >> 4; tb < TSTEPS; tb += THREADS >> 4) {
            float2 xv = *(const float2*)&x[(size_t)(rb + row) * (2 * TSTEPS) + tb * 2];
            __bf16 x0h = (__bf16)xv.x, x1h = (__bf16)xv.y;
            __bf16 x0r = (__bf16)(xv.x - (float)x0h);
            __bf16 x1r = (__bf16)(xv.y - (float)x1h);
            uint2 d;
            d.x = (unsigned)__builtin_bit_cast(unsigned short, x0h) |
                  ((unsigned)__builtin_bit_cast(unsigned short, x1h) << 16);
            d.y = (unsigned)__builtin_bit_cast(unsigned short, x0r) |
                  ((unsigned)__builtin_bit_cast(unsigned short, x1r) << 16);
            xa[tb * BR + row] = d;
        }
    }
    for (int i = tid; i < BR * HPITCH; i += THREADS) h_lds[0][i] = (__bf16)0.0f;

    // ---- weights -> registers, pre-scaled so MFMA outputs are exp2-ready ----
    // gate scale: i,f,o -> -log2(e); g -> -2*log2(e)
    // Transposed MFMA: bfrag/bfx = A operand (m = gate col = wave*16 + l15),
    // h/x = B operand (n = batch row = l15).
    // C layout: n(=lane&15) = batch row, m(=quad*4+reg) = gate-col offset.
    bf16x8 bfrag[4][4];   // [gate][kchunk] scaled W_hh (later W_eff)
    B8 bfx[4];            // scaled W_ih + bias hi/lo, quad0 k-slots only (A operand)
    float gs[4];
    const float fcb0 = fc_b[0], fcb1 = fc_b[1];
    const int ub    = wave * 16 + l15;        // A-layout gate col (weights)
    const int cbase = wave * 16 + quad * 4;   // C-layout gate-col base (ew/h-write)
#pragma unroll
    for (int g = 0; g < 4; ++g) {
        gs[g] = (g == 2) ? -L2E2 : -L2E;
        const int cg = g * HIDDEN + ub;
        const float w0 = W_ih[cg * 2 + 0];
        const float w1 = W_ih[cg * 2 + 1];
        const float bs = b_ih[cg] + b_hh[cg];
#pragma unroll
        for (int ks = 0; ks < 4; ++ks) {
            const float* wp = W_hh + (size_t)cg * HIDDEN + ks * 32 + quad * 8;
            bf16x8 bb;
#pragma unroll
            for (int j = 0; j < 8; ++j) bb[j] = (__bf16)(gs[g] * wp[j]);
            bfrag[g][ks] = bb;
        }
        B8 t; t.i = make_int4(0, 0, 0, 0);
        if (quad == 0) {
            const float w0s = gs[g] * w0, w1s = gs[g] * w1, bss = gs[g] * bs;
            __bf16 w0h = (__bf16)w0s, w1h = (__bf16)w1s;
            __bf16 w0l = (__bf16)(w0s - (float)w0h);
            __bf16 w1l = (__bf16)(w1s - (float)w1h);
            __bf16 bh  = (__bf16)bss;
            __bf16 bl  = (__bf16)(bss - (float)bh);
            bf16x8 bv = {w0h, w1h, bh, bl, w0h, w1h, w0l, w1l};
            t.v = bv;
        }
        bfx[g] = t;
    }

    // ---- STATIC ASYMMETRIC PRIORITY: one hi-prio wave per SIMD pair ----
    // R3's counters (35% Mfma + 55% VALU + 10% idle = 100%) show the matrix
    // pipe's round-robin arbitration phase-locks the 2 barrier-aligned waves:
    // both finish MFMAs together, then serialize on the VALU. Raising ONE
    // wave's priority makes its 20 MFMAs complete first (~356cy), so its ew
    // overlaps the sibling's MFMA phase — a restoring force applied every step.
    if (wave >= 4) SETPRIO(1);

    const unsigned ones2 = 0x3F803F80u;  // bf16(1.0) x2
    const int hrow = l15 * HPITCH;
    f32x2 cst[2] = {{0.f, 0.f}, {0.f, 0.f}};   // cell state: pair p = cols cbase+2p..+1

    auto pk2 = [](f32x2 hn) -> unsigned {
        return (unsigned)__builtin_bit_cast(unsigned short, (__bf16)hn.x)
             | ((unsigned)__builtin_bit_cast(unsigned short, (__bf16)hn.y) << 16);
    };

    // ew tail: 16 gate exps, then per-pair combine (tanh-c exp inline), pack, b64 write.
    auto ewTail = [&](floatx4 a0, floatx4 a1, floatx4 a2, floatx4 a3, __bf16* hd) {
        floatx4 ea, ec, eb, eo;
#pragma unroll
        for (int r = 0; r < 4; ++r) ea[r] = EXP2F(a0[r]);   // e^-i
#pragma unroll
        for (int r = 0; r < 4; ++r) ec[r] = EXP2F(a1[r]);   // e^-f
#pragma unroll
        for (int r = 0; r < 4; ++r) eb[r] = EXP2F(a2[r]);   // e^-2g
#pragma unroll
        for (int r = 0; r < 4; ++r) eo[r] = EXP2F(a3[r]);   // e^-o
        unsigned wArr[2];
#pragma unroll
        for (int p = 0; p < 2; ++p) {
            const f32x2 eap = {ea[2 * p], ea[2 * p + 1]};
            const f32x2 ebp = {eb[2 * p], eb[2 * p + 1]};
            const f32x2 ecp = {ec[2 * p], ec[2 * p + 1]};
            const f32x2 eop = {eo[2 * p], eo[2 * p + 1]};
            const f32x2 A1 = 1.f + eap, B1 = 1.f + ebp, C1 = 1.f + ecp;
            const f32x2 P  = A1 * B1;
            const f32x2 PC = P * C1;
            f32x2 R;                                        // batched: 1 rcp per pair
            { const float I = RCPF(PC.x * PC.y); R.x = I * PC.y; R.y = I * PC.x; }
            const f32x2 sfv = P * R;                        // sigmoid(f)
            const f32x2 igv = (1.f - ebp) * (C1 * R);       // sigmoid(i)*tanh(g)
            const f32x2 cn  = sfv * cst[p] + igv;
            cst[p] = cn;
            const f32x2 am = -L2E2 * cn;
            f32x2 ed;
            ed.x = EXP2F(fminf(am.x, 29.f));                // c clamped at -10 (tanh err < 4e-9)
            ed.y = EXP2F(fminf(am.y, 29.f));
            const f32x2 E = (1.f + ed) * (1.f + eop);
            f32x2 R2;                                       // batched: 1 rcp per pair
            { const float J = RCPF(E.x * E.y); R2.x = J * E.y; R2.y = J * E.x; }
            const f32x2 hn = (1.f - ed) * R2;               // sigmoid(o)*tanh(c)
            wArr[p] = pk2(hn);
        }
        uint2 wv; wv.x = wArr[0]; wv.y = wArr[1];
        *(uint2*)&hd[hrow + cbase] = wv;                    // 4 cols, one b64
    };

    // Encode cell: x+bias via MFMA on the (underused) matrix pipe; ks-outer/g-inner
    // gives 4 independent accumulation chains. Prefetch next xa under ew+barrier.
    // NO per-phase setprio: the static wave-level asymmetry must not be overridden.
    auto cellE = [&](const __bf16* hs, __bf16* hd, uint2 xd, int tn) -> uint2 {
        B8 xf; xf.i = make_int4((int)xd.x, (int)ones2, (int)xd.y, (int)xd.x);
        bf16x8 af[4];
#pragma unroll
        for (int ks = 0; ks < 4; ++ks)
            af[ks] = *(const bf16x8*)&hs[hrow + ks * 32 + quad * 8];
        const floatx4 z = {0.f, 0.f, 0.f, 0.f};
        floatx4 acc[4];
#pragma unroll
        for (int g = 0; g < 4; ++g)
            acc[g] = __builtin_amdgcn_mfma_f32_16x16x32_bf16(bfx[g].v, xf.v, z, 0, 0, 0);
#pragma unroll
        for (int ks = 0; ks < 4; ++ks)
#pragma unroll
            for (int g = 0; g < 4; ++g)
                acc[g] = __builtin_amdgcn_mfma_f32_16x16x32_bf16(bfrag[g][ks], af[ks], acc[g], 0, 0, 0);
        const int ts = (tn < TSTEPS) ? tn : 0;
        const uint2 xn = xa[ts * BR + l15];                 // prefetch (consumed next cell)
        ewTail(acc[0], acc[1], acc[2], acc[3], hd);
        __syncthreads();
        return xn;
    };

    __syncthreads();

    // ================= encode: 512 steps =================
    uint2 xd = xa[l15];                                     // t = 0
    for (int t = 0; t < TSTEPS; t += 2) {
        xd = cellE(h_lds[0], h_lds[1], xd, t + 1);
        xd = cellE(h_lds[1], h_lds[0], xd, t + 2);
    }

    // ========== transition: fold fc into weights =========
    // W_eff = gs*(W_hh + W_ih*fc_w) (A-layout fold); b_eff in exact fp32 C-layout.
    floatx4 beff[4];
#pragma unroll
    for (int g = 0; g < 4; ++g) {
        const int cgA = g * HIDDEN + ub;
        const float wi0 = W_ih[cgA * 2 + 0];
        const float wi1 = W_ih[cgA * 2 + 1];
#pragma unroll
        for (int ks = 0; ks < 4; ++ks) {
            const int k0 = ks * 32 + quad * 8;
            bf16x8 bb = bfrag[g][ks];
#pragma unroll
            for (int j = 0; j < 8; ++j)
                bb[j] = (__bf16)((float)bb[j] + gs[g] * (wi0 * fcw_lds[0][k0 + j]
                                                       + wi1 * fcw_lds[1][k0 + j]));
            bfrag[g][ks] = bb;
        }
        floatx4 v;
#pragma unroll
        for (int r = 0; r < 4; ++r) {
            const int cg = g * HIDDEN + cbase + r;          // C-layout col
            v[r] = gs[g] * (b_ih[cg] + b_hh[cg]
                          + W_ih[cg * 2 + 0] * fcb0 + W_ih[cg * 2 + 1] * fcb1);
        }
        beff[g] = v;
    }

    auto cellF = [&](const __bf16* hs, __bf16* hd) {
        bf16x8 af[4];
#pragma unroll
        for (int ks = 0; ks < 4; ++ks)
            af[ks] = *(const bf16x8*)&hs[hrow + ks * 32 + quad * 8];
        floatx4 acc[4];
#pragma unroll
        for (int g = 0; g < 4; ++g) acc[g] = beff[g];       // exact fp32 scaled bias
#pragma unroll
        for (int ks = 0; ks < 4; ++ks)
#pragma unroll
            for (int g = 0; g < 4; ++g)
                acc[g] = __builtin_amdgcn_mfma_f32_16x16x32_bf16(bfrag[g][ks], af[ks], acc[g], 0, 0, 0);
        ewTail(acc[0], acc[1], acc[2], acc[3], hd);
        __syncthreads();
    };

    // y output only (no feedback): wave0 computes while others run MFMA
    auto emitY = [&](const __bf16* hs, int f) {
        if (wave == 0) {
            const int r = lane & 15, seg = lane >> 4;
            const __bf16* hp = &hs[r * HPITCH + seg * 32];
            float p0 = 0.f, p1 = 0.f;
#pragma unroll
            for (int js = 0; js < 4; ++js) {
                bf16x8 hv = *(const bf16x8*)&hp[js * 8];
                const float4* f0 = (const float4*)&fcw_lds[0][seg * 32 + js * 8];
                const float4* f1 = (const float4*)&fcw_lds[1][seg * 32 + js * 8];
                float4 a0 = f0[0], b0 = f0[1], a1 = f1[0], b1 = f1[1];
                p0 += (float)hv[0]*a0.x + (float)hv[1]*a0.y + (float)hv[2]*a0.z + (float)hv[3]*a0.w
                    + (float)hv[4]*b0.x + (float)hv[5]*b0.y + (float)hv[6]*b0.z + (float)hv[7]*b0.w;
                p1 += (float)hv[0]*a1.x + (float)hv[1]*a1.y + (float)hv[2]*a1.z + (float)hv[3]*a1.w
                    + (float)hv[4]*b1.x + (float)hv[5]*b1.y + (float)hv[6]*b1.z + (float)hv[7]*b1.w;
            }
            p0 += __shfl_xor(p0, 16); p0 += __shfl_xor(p0, 32);
            p1 += __shfl_xor(p1, 16); p1 += __shfl_xor(p1, 32);
            if (seg == 0) {
                float* op = &out[(size_t)(rb + r) * (2 * NFUT) + f * 2];
                op[0] = p0 + fcb0;
                op[1] = p1 + fcb1;
            }
        }
    };

    // ================= forecast: 50 steps ================
    for (int f = 0; f < NFUT; f += 2) {
        emitY(h_lds[0], f);
        cellF(h_lds[0], h_lds[1]);
        emitY(h_lds[1], f + 1);
        cellF(h_lds[1], h_lds[0]);
    }
}

extern "C" void kernel_launch(void* const* d_in, const int* in_sizes, int n_in,
                              void* d_out, int out_size, void* d_ws, size_t ws_size,
                              hipStream_t stream) {
    const float* x    = (const float*)d_in[0];
    const float* W_ih = (const float*)d_in[1];
    const float* W_hh = (const float*)d_in[2];
    const float* b_ih = (const float*)d_in[3];
    const float* b_hh = (const float*)d_in[4];
    const float* fc_w = (const float*)d_in[5];
    const float* fc_b = (const float*)d_in[6];
    float* out = (float*)d_out;

    const int B = in_sizes[0] / (TSTEPS * 2);   // 4096
    const int grid = B / BR;                    // 256 blocks, 1 per CU
    lstm_forecast_kernel<<<grid, THREADS, 0, stream>>>(x, W_ih, W_hh, b_ih, b_hh, fc_w, fc_b, out);
}